// Round 5
// baseline (262.120 us; speedup 1.0000x reference)
//
#include <hip/hip_runtime.h>
#include <hip/hip_cooperative_groups.h>

namespace cg = cooperative_groups;

#define NB 8
#define NN 20000
#define NE 640000
#define NF 8
#define NH 128
#define CAP 2048              // max collected in-edges per graph (mean 32)
#define VPG (NE / 4)          // int4 vectors per graph (dst half) = 160000
#define WPG 64                // workgroups per graph
#define NBLK (NB * WPG)       // 512 blocks total (2/CU — co-resident)
#define CHUNK (VPG / WPG)     // 2500 int4 per WG
#define BMW ((NN + 31) / 32)  // node-bitmap words = 625

// ---------------- workspace layout ----------------
// [0, 64)              : cnt[NB]
// [64, 64+NB*CAP*4)    : lst[NB][CAP]
// [WS_DEG_OFF, ...)    : deg[NB][NN] (only tracked slots ever touched; lazy-zeroed)
#define WS_CNT_OFF  0
#define WS_LST_OFF  64
#define WS_DEG_OFF  (64 + NB * CAP * 4)

__global__ __launch_bounds__(256, 2) void fused_gcn(
    const float* __restrict__ x, const int* __restrict__ ei,
    const int* __restrict__ nidx,
    const float* __restrict__ W1, const float* __restrict__ b1,
    const float* __restrict__ W2, const float* __restrict__ b2,
    const float* __restrict__ W3, const float* __restrict__ b3,
    const float* __restrict__ Wl, const float* __restrict__ bl,
    int* __restrict__ cnt, int* __restrict__ lst, int* __restrict__ deg,
    float* __restrict__ out)
{
    cg::grid_group grid = cg::this_grid();
    const int tid = threadIdx.x;
    const int b   = blockIdx.x / WPG;
    const int w   = blockIdx.x % WPG;
    const int tgt = nidx[b];

    // ---- phase 0: zero counters + target deg slots (covers n==0 case) ----
    if (blockIdx.x == 0 && tid < NB) {
        cnt[tid] = 0;
        deg[tid * NN + nidx[tid]] = 0;
    }
    grid.sync();

    const int* dstp  = ei + (size_t)b * 2 * NE + NE;
    const int* srcp  = ei + (size_t)b * 2 * NE;
    const int  start = w * CHUNK;

    // ---- phase 1: collect srcs of in-edges to target; lazy-zero their deg ----
    for (int v = start + tid; v < start + CHUNK; v += 256) {
        int4 d = ((const int4*)dstp)[v];                 // coalesced 16B/lane
        if (d.x == tgt || d.y == tgt || d.z == tgt || d.w == tgt) {
            int e0 = v * 4;
            int dd[4] = {d.x, d.y, d.z, d.w};
#pragma unroll
            for (int c = 0; c < 4; ++c) {
                if (dd[c] == tgt) {
                    int pos = atomicAdd(&cnt[b], 1);
                    int s = srcp[e0 + c];
                    if (pos < CAP) lst[b * CAP + pos] = s;
                    deg[b * NN + s] = 0;                 // lazy zero
                }
            }
        }
    }
    __threadfence();
    grid.sync();

    // ---- phase 2: count in-degree of tracked nodes (LDS bitmap filter) ----
    __shared__ unsigned bm[BMW];
    for (int i = tid; i < BMW; i += 256) bm[i] = 0u;
    __syncthreads();
    int n = cnt[b]; if (n > CAP) n = CAP;
    for (int i = tid; i < n + 1; i += 256) {
        int node = (i == n) ? tgt : lst[b * CAP + i];
        atomicOr(&bm[node >> 5], 1u << (node & 31));
    }
    __syncthreads();
    int* degb = deg + b * NN;
    for (int v = start + tid; v < start + CHUNK; v += 256) {
        int4 d = ((const int4*)dstp)[v];                 // L2-warm re-read
        if ((bm[d.x >> 5] >> (d.x & 31)) & 1u) atomicAdd(&degb[d.x], 1);
        if ((bm[d.y >> 5] >> (d.y & 31)) & 1u) atomicAdd(&degb[d.y], 1);
        if ((bm[d.z >> 5] >> (d.z & 31)) & 1u) atomicAdd(&degb[d.z], 1);
        if ((bm[d.w >> 5] >> (d.w & 31)) & 1u) atomicAdd(&degb[d.w], 1);
    }
    __threadfence();
    grid.sync();

    // ---- phase 3: per-graph GCN+MLP tail on blocks 0..NB-1 ----
    if (blockIdx.x < NB) {
        const int g = blockIdx.x;
        const int t = nidx[g];
        const int j = tid;
        int m = cnt[g]; if (m > CAP) m = CAP;
        const int*   mylst = lst + g * CAP;
        const int*   mydeg = deg + g * NN;
        const float* xb    = x + (size_t)g * NN * NF;
        __shared__ float h1[NH], h2[NH], h3[NH];

        const float dinv_t = rsqrtf((float)(mydeg[t] + 1));
        if (j < NH) {
            float ht = 0.f;
#pragma unroll
            for (int k = 0; k < NF; ++k) ht += xb[(size_t)t * NF + k] * W1[k * NH + j];
            float acc = ht * dinv_t * dinv_t;
            for (int i = 0; i < m; ++i) {
                int s = mylst[i];
                float dinv_s = rsqrtf((float)(mydeg[s] + 1));
                float hs = 0.f;
#pragma unroll
                for (int k = 0; k < NF; ++k) hs += xb[(size_t)s * NF + k] * W1[k * NH + j];
                acc += hs * (dinv_s * dinv_t);
            }
            float v1 = acc + b1[j];
            h1[j] = v1 > 0.f ? v1 : 0.f;
        }
        __syncthreads();
        if (j < NH) {
            float a2 = b2[j];
            for (int k = 0; k < NH; ++k) a2 += h1[k] * W2[k * NH + j];
            h2[j] = a2 > 0.f ? a2 : 0.f;
        }
        __syncthreads();
        if (j < NH) {
            float a3 = b3[j];
            for (int k = 0; k < NH; ++k) a3 += h2[k] * W3[k * NH + j];
            h3[j] = a3 > 0.f ? a3 : 0.f;
        }
        __syncthreads();
        if (j < 2) {
            float o = bl[j];
            for (int k = 0; k < NH; ++k) o += h3[k] * Wl[k * 2 + j];
            out[g * 2 + j] = o;
        }
    }
}

extern "C" void kernel_launch(void* const* d_in, const int* in_sizes, int n_in,
                              void* d_out, int out_size, void* d_ws, size_t ws_size,
                              hipStream_t stream) {
    const float* x    = (const float*)d_in[0];
    const int*   ei   = (const int*)d_in[1];      // integer inputs arrive as int32
    const int*   nidx = (const int*)d_in[2];
    const float* W1 = (const float*)d_in[3];
    const float* b1 = (const float*)d_in[4];
    const float* W2 = (const float*)d_in[5];
    const float* b2 = (const float*)d_in[6];
    const float* W3 = (const float*)d_in[7];
    const float* b3 = (const float*)d_in[8];
    const float* Wl = (const float*)d_in[9];
    const float* bl = (const float*)d_in[10];
    float* out = (float*)d_out;

    char* ws  = (char*)d_ws;
    int*  cnt = (int*)(ws + WS_CNT_OFF);
    int*  lst = (int*)(ws + WS_LST_OFF);
    int*  deg = (int*)(ws + WS_DEG_OFF);

    void* args[] = {&x, &ei, &nidx, &W1, &b1, &W2, &b2, &W3, &b3, &Wl, &bl,
                    &cnt, &lst, &deg, &out};
    hipLaunchCooperativeKernel((void*)fused_gcn, dim3(NBLK), dim3(256),
                               args, 0, stream);
}

// Round 6
// 88.656 us; speedup vs baseline: 2.9566x; 2.9566x over previous
//
#include <hip/hip_runtime.h>

#define NB 8
#define NN 20000
#define NE 640000
#define NF 8
#define NH 128
#define VPG (NE / 4)          // int4 vectors per graph (dst half) = 160000
#define WPG 128               // workgroups per graph
#define CHUNK_V (VPG / WPG)   // 1250 int4 per WG
#define SLOT 32               // per-WG private list capacity (mean matches 0.25)
#define BMW ((NN + 31) / 32)  // node-bitmap words = 625
#define MAXTRK 1024           // compact tracked-list cap (realistic n ~ 32)

// ---------------- workspace layout ----------------
// [0, 4096)        : cntblk[NB][WPG]
// [4096, 4160)     : done[NB] (ticket counters, zeroed by K1)
// [4160, +131072)  : lst[NB][WPG][SLOT]
// [WS_DEG_OFF, ..) : deg[NB][NN] (only tracked slots touched; lazy-zeroed by K1)
#define WS_CNT_OFF  0
#define WS_DONE_OFF 4096
#define WS_LST_OFF  4160
#define WS_DEG_OFF  (4160 + NB * WPG * SLOT * 4)

// K1: scan dst stream; per-block private collection (no global atomics, no init
// kernel needed — every block unconditionally writes its own cntblk slot).
__global__ __launch_bounds__(256) void collect(
    const int* __restrict__ ei, const int* __restrict__ nidx,
    int* __restrict__ cntblk, int* __restrict__ lst,
    int* __restrict__ deg, int* __restrict__ done) {
    const int bid = blockIdx.x, b = bid >> 7, w = bid & (WPG - 1);
    const int tid = threadIdx.x;
    const int tgt = nidx[b];
    __shared__ int lcnt;
    __shared__ int lbuf[SLOT];
    if (tid == 0) {
        lcnt = 0;
        if (w == 0) { done[b] = 0; deg[b * NN + tgt] = 0; }
    }
    __syncthreads();

    const int* dstp = ei + (size_t)b * 2 * NE + NE;
    const int* srcp = ei + (size_t)b * 2 * NE;
    const int start = w * CHUNK_V;
    for (int v = start + tid; v < start + CHUNK_V; v += 256) {
        int4 d = ((const int4*)dstp)[v];                 // coalesced 16B/lane
        if (d.x == tgt || d.y == tgt || d.z == tgt || d.w == tgt) {
            int e0 = v * 4;
            int dd[4] = {d.x, d.y, d.z, d.w};
#pragma unroll
            for (int c = 0; c < 4; ++c) {
                if (dd[c] == tgt) {
                    int s = srcp[e0 + c];
                    int p = atomicAdd(&lcnt, 1);         // LDS atomic only
                    if (p < SLOT) lbuf[p] = s;
                    deg[b * NN + s] = 0;                 // lazy zero tracked slot
                }
            }
        }
    }
    __syncthreads();
    int m = lcnt > SLOT ? SLOT : lcnt;
    if (tid == 0) cntblk[b * WPG + w] = m;
    if (tid < m) lst[(b * WPG + w) * SLOT + tid] = lbuf[tid];
}

// K2: build bitmap+compact list from per-block lists, count tracked degrees
// over own chunk (L2-warm), then last-ticket WG per graph runs the MLP tail.
__global__ __launch_bounds__(256) void count_tail(
    const float* __restrict__ x, const int* __restrict__ ei,
    const int* __restrict__ nidx,
    const float* __restrict__ W1, const float* __restrict__ b1,
    const float* __restrict__ W2, const float* __restrict__ b2,
    const float* __restrict__ W3, const float* __restrict__ b3,
    const float* __restrict__ Wl, const float* __restrict__ bl,
    int* __restrict__ cntblk, int* __restrict__ lst,
    int* __restrict__ deg, int* __restrict__ done, float* __restrict__ out) {
    const int bid = blockIdx.x, b = bid >> 7, w = bid & (WPG - 1);
    const int tid = threadIdx.x;
    const int tgt = nidx[b];

    __shared__ unsigned bm[BMW];
    __shared__ int carr[WPG], coff[WPG];
    __shared__ int ntot;
    __shared__ int compact[MAXTRK];

    for (int i = tid; i < BMW; i += 256) bm[i] = 0u;
    if (tid < WPG) carr[tid] = cntblk[b * WPG + tid];
    __syncthreads();
    if (tid < WPG) {
        int o = 0;
        for (int i = 0; i < tid; ++i) o += carr[i];
        coff[tid] = o;
        if (tid == WPG - 1) ntot = o + carr[tid];
    }
    __syncthreads();
    int n = ntot; if (n > MAXTRK) n = MAXTRK;
    for (int idx = tid; idx < WPG * SLOT; idx += 256) {
        int w2 = idx / SLOT, s = idx % SLOT;
        if (s < carr[w2]) {
            int val = lst[(b * WPG + w2) * SLOT + s];
            int pos = coff[w2] + s;
            if (pos < MAXTRK) compact[pos] = val;
            atomicOr(&bm[val >> 5], 1u << (val & 31));
        }
    }
    if (tid == 0) atomicOr(&bm[tgt >> 5], 1u << (tgt & 31));
    __syncthreads();

    // count phase: re-scan own chunk (same block->XCD map as K1 -> L2-warm)
    const int* dstp = ei + (size_t)b * 2 * NE + NE;
    int* degb = deg + b * NN;
    const int start = w * CHUNK_V;
    for (int v = start + tid; v < start + CHUNK_V; v += 256) {
        int4 d = ((const int4*)dstp)[v];
        if ((bm[d.x >> 5] >> (d.x & 31)) & 1u) atomicAdd(&degb[d.x], 1);
        if ((bm[d.y >> 5] >> (d.y & 31)) & 1u) atomicAdd(&degb[d.y], 1);
        if ((bm[d.z >> 5] >> (d.z & 31)) & 1u) atomicAdd(&degb[d.z], 1);
        if ((bm[d.w >> 5] >> (d.w & 31)) & 1u) atomicAdd(&degb[d.w], 1);
    }
    __threadfence();
    __syncthreads();
    __shared__ int lastf;
    if (tid == 0) {
        int t = atomicAdd(&done[b], 1);
        lastf = (t == WPG - 1);
    }
    __syncthreads();
    if (!lastf) return;

    // ---- tail: GCN layer at target + 3-layer MLP (winning WG only) ----
    __shared__ float dinv[MAXTRK + 1];
    for (int i = tid; i <= n; i += 256) {
        int node = (i == n) ? tgt : compact[i];
        int dv = atomicAdd(&degb[node], 0);   // coherent read at device scope
        dinv[i] = rsqrtf((float)(dv + 1));
    }
    __syncthreads();

    __shared__ float h1[NH], h2[NH], h3[NH];
    const float* xb = x + (size_t)b * NN * NF;
    const float dt = dinv[n];
    const int j = tid;
    if (j < NH) {
        float ht = 0.f;
#pragma unroll
        for (int k = 0; k < NF; ++k) ht += xb[(size_t)tgt * NF + k] * W1[k * NH + j];
        float acc = ht * dt * dt;
        for (int i = 0; i < n; ++i) {
            int s = compact[i];
            float hs = 0.f;
#pragma unroll
            for (int k = 0; k < NF; ++k) hs += xb[(size_t)s * NF + k] * W1[k * NH + j];
            acc += hs * (dinv[i] * dt);
        }
        float v1 = acc + b1[j];
        h1[j] = v1 > 0.f ? v1 : 0.f;
    }
    __syncthreads();
    if (j < NH) {
        float a2 = b2[j];
        for (int k = 0; k < NH; ++k) a2 += h1[k] * W2[k * NH + j];
        h2[j] = a2 > 0.f ? a2 : 0.f;
    }
    __syncthreads();
    if (j < NH) {
        float a3 = b3[j];
        for (int k = 0; k < NH; ++k) a3 += h2[k] * W3[k * NH + j];
        h3[j] = a3 > 0.f ? a3 : 0.f;
    }
    __syncthreads();
    if (j < 2) {
        float o = bl[j];
        for (int k = 0; k < NH; ++k) o += h3[k] * Wl[k * 2 + j];
        out[b * 2 + j] = o;
    }
}

extern "C" void kernel_launch(void* const* d_in, const int* in_sizes, int n_in,
                              void* d_out, int out_size, void* d_ws, size_t ws_size,
                              hipStream_t stream) {
    const float* x    = (const float*)d_in[0];
    const int*   ei   = (const int*)d_in[1];      // integer inputs arrive as int32
    const int*   nidx = (const int*)d_in[2];
    const float* W1 = (const float*)d_in[3];
    const float* b1 = (const float*)d_in[4];
    const float* W2 = (const float*)d_in[5];
    const float* b2 = (const float*)d_in[6];
    const float* W3 = (const float*)d_in[7];
    const float* b3 = (const float*)d_in[8];
    const float* Wl = (const float*)d_in[9];
    const float* bl = (const float*)d_in[10];
    float* out = (float*)d_out;

    char* ws     = (char*)d_ws;
    int*  cntblk = (int*)(ws + WS_CNT_OFF);
    int*  done   = (int*)(ws + WS_DONE_OFF);
    int*  lst    = (int*)(ws + WS_LST_OFF);
    int*  deg    = (int*)(ws + WS_DEG_OFF);

    collect<<<NB * WPG, 256, 0, stream>>>(ei, nidx, cntblk, lst, deg, done);

    count_tail<<<NB * WPG, 256, 0, stream>>>(x, ei, nidx, W1, b1, W2, b2,
                                             W3, b3, Wl, bl,
                                             cntblk, lst, deg, done, out);
}

// Round 7
// 38.790 us; speedup vs baseline: 6.7574x; 2.2856x over previous
//
#include <hip/hip_runtime.h>

#define NB 8
#define NN 20000
#define NE 640000
#define NF 8
#define NH 128
#define VPG (NE / 4)          // int4 vectors per graph (dst half) = 160000
#define WPG 128               // workgroups per graph
#define CHUNK_V (VPG / WPG)   // 1250 int4 per WG
#define SLOT 32               // per-WG private list capacity (mean matches 0.25)
#define BMW ((NN + 31) / 32)  // node-bitmap words = 625
#define MAXTRK 1024           // compact tracked-list cap (realistic n ~ 32)

// ---------------- workspace layout ----------------
// [0, 4096)        : cntblk[NB][WPG]
// [4096, 4160)     : done[NB] (ticket counters, zeroed by K1)
// [4160, +131072)  : lst[NB][WPG][SLOT]
// [WS_DEG_OFF, ..) : deg[NB][NN] (only tracked slots touched; lazy-zeroed by K1)
#define WS_CNT_OFF  0
#define WS_DONE_OFF 4096
#define WS_LST_OFF  4160
#define WS_DEG_OFF  (4160 + NB * WPG * SLOT * 4)

// K1: scan dst stream; per-block private collection (LDS atomics only).
__global__ __launch_bounds__(256) void collect(
    const int* __restrict__ ei, const int* __restrict__ nidx,
    int* __restrict__ cntblk, int* __restrict__ lst,
    int* __restrict__ deg, int* __restrict__ done) {
    const int bid = blockIdx.x, b = bid >> 7, w = bid & (WPG - 1);
    const int tid = threadIdx.x;
    const int tgt = nidx[b];
    __shared__ int lcnt;
    __shared__ int lbuf[SLOT];
    if (tid == 0) {
        lcnt = 0;
        if (w == 0) { done[b] = 0; deg[b * NN + tgt] = 0; }
    }
    __syncthreads();

    const int* dstp = ei + (size_t)b * 2 * NE + NE;
    const int* srcp = ei + (size_t)b * 2 * NE;
    const int start = w * CHUNK_V;
    for (int v = start + tid; v < start + CHUNK_V; v += 256) {
        int4 d = ((const int4*)dstp)[v];                 // coalesced 16B/lane
        if (d.x == tgt || d.y == tgt || d.z == tgt || d.w == tgt) {
            int e0 = v * 4;
            int dd[4] = {d.x, d.y, d.z, d.w};
#pragma unroll
            for (int c = 0; c < 4; ++c) {
                if (dd[c] == tgt) {
                    int s = srcp[e0 + c];
                    int p = atomicAdd(&lcnt, 1);         // LDS atomic only
                    if (p < SLOT) lbuf[p] = s;
                    deg[b * NN + s] = 0;                 // lazy zero tracked slot
                }
            }
        }
    }
    __syncthreads();
    int m = lcnt > SLOT ? SLOT : lcnt;
    if (tid == 0) cntblk[b * WPG + w] = m;
    if (tid < m) lst[(b * WPG + w) * SLOT + tid] = lbuf[tid];
}

// K2: build bitmap+compact list from per-block lists, count tracked degrees
// over own chunk (L2-warm), then last-ticket WG per graph runs the MLP tail.
// NO __threadfence: all cross-block traffic is device-scope atomics (coherent
// at the coherence point); s_waitcnt vmcnt(0) before the ticket orders them.
__global__ __launch_bounds__(256) void count_tail(
    const float* __restrict__ x, const int* __restrict__ ei,
    const int* __restrict__ nidx,
    const float* __restrict__ W1, const float* __restrict__ b1,
    const float* __restrict__ W2, const float* __restrict__ b2,
    const float* __restrict__ W3, const float* __restrict__ b3,
    const float* __restrict__ Wl, const float* __restrict__ bl,
    int* __restrict__ cntblk, int* __restrict__ lst,
    int* __restrict__ deg, int* __restrict__ done, float* __restrict__ out) {
    const int bid = blockIdx.x, b = bid >> 7, w = bid & (WPG - 1);
    const int tid = threadIdx.x;
    const int tgt = nidx[b];

    __shared__ unsigned bm[BMW];
    __shared__ int carr[WPG], coff[WPG];
    __shared__ int ntot;
    __shared__ int compact[MAXTRK];

    for (int i = tid; i < BMW; i += 256) bm[i] = 0u;
    if (tid < WPG) carr[tid] = cntblk[b * WPG + tid];
    __syncthreads();
    if (tid < WPG) {
        int o = 0;
        for (int i = 0; i < tid; ++i) o += carr[i];
        coff[tid] = o;
        if (tid == WPG - 1) ntot = o + carr[tid];
    }
    __syncthreads();
    int n = ntot; if (n > MAXTRK) n = MAXTRK;
    for (int idx = tid; idx < WPG * SLOT; idx += 256) {
        int w2 = idx / SLOT, s = idx % SLOT;
        if (s < carr[w2]) {
            int val = lst[(b * WPG + w2) * SLOT + s];
            int pos = coff[w2] + s;
            if (pos < MAXTRK) compact[pos] = val;
            atomicOr(&bm[val >> 5], 1u << (val & 31));
        }
    }
    if (tid == 0) atomicOr(&bm[tgt >> 5], 1u << (tgt & 31));
    __syncthreads();

    // count phase: re-scan own chunk (same block->XCD map as K1 -> L2-warm)
    const int* dstp = ei + (size_t)b * 2 * NE + NE;
    int* degb = deg + b * NN;
    const int start = w * CHUNK_V;
    for (int v = start + tid; v < start + CHUNK_V; v += 256) {
        int4 d = ((const int4*)dstp)[v];
        if ((bm[d.x >> 5] >> (d.x & 31)) & 1u) atomicAdd(&degb[d.x], 1);
        if ((bm[d.y >> 5] >> (d.y & 31)) & 1u) atomicAdd(&degb[d.y], 1);
        if ((bm[d.z >> 5] >> (d.z & 31)) & 1u) atomicAdd(&degb[d.z], 1);
        if ((bm[d.w >> 5] >> (d.w & 31)) & 1u) atomicAdd(&degb[d.w], 1);
    }
    // ensure this block's deg atomics have completed (reached coherence point)
    asm volatile("s_waitcnt vmcnt(0)" ::: "memory");
    __syncthreads();
    __shared__ int lastf;
    if (tid == 0) {
        int t = atomicAdd(&done[b], 1);
        lastf = (t == WPG - 1);
    }
    __syncthreads();
    if (!lastf) return;

    // ---- tail: GCN layer at target + 3-layer MLP (winning WG only) ----
    __shared__ float dinv[MAXTRK + 1];
    for (int i = tid; i <= n; i += 256) {
        int node = (i == n) ? tgt : compact[i];
        int dv = atomicAdd(&degb[node], 0);   // coherent read at device scope
        dinv[i] = rsqrtf((float)(dv + 1));
    }
    __syncthreads();

    __shared__ float h1[NH], h2[NH], h3[NH];
    const float* xb = x + (size_t)b * NN * NF;
    const float dt = dinv[n];
    const int j = tid;
    if (j < NH) {
        float ht = 0.f;
#pragma unroll
        for (int k = 0; k < NF; ++k) ht += xb[(size_t)tgt * NF + k] * W1[k * NH + j];
        float acc = ht * dt * dt;
        for (int i = 0; i < n; ++i) {
            int s = compact[i];
            float hs = 0.f;
#pragma unroll
            for (int k = 0; k < NF; ++k) hs += xb[(size_t)s * NF + k] * W1[k * NH + j];
            acc += hs * (dinv[i] * dt);
        }
        float v1 = acc + b1[j];
        h1[j] = v1 > 0.f ? v1 : 0.f;
    }
    __syncthreads();
    if (j < NH) {
        float a2 = b2[j];
        for (int k = 0; k < NH; ++k) a2 += h1[k] * W2[k * NH + j];
        h2[j] = a2 > 0.f ? a2 : 0.f;
    }
    __syncthreads();
    if (j < NH) {
        float a3 = b3[j];
        for (int k = 0; k < NH; ++k) a3 += h2[k] * W3[k * NH + j];
        h3[j] = a3 > 0.f ? a3 : 0.f;
    }
    __syncthreads();
    if (j < 2) {
        float o = bl[j];
        for (int k = 0; k < NH; ++k) o += h3[k] * Wl[k * 2 + j];
        out[b * 2 + j] = o;
    }
}

extern "C" void kernel_launch(void* const* d_in, const int* in_sizes, int n_in,
                              void* d_out, int out_size, void* d_ws, size_t ws_size,
                              hipStream_t stream) {
    const float* x    = (const float*)d_in[0];
    const int*   ei   = (const int*)d_in[1];      // integer inputs arrive as int32
    const int*   nidx = (const int*)d_in[2];
    const float* W1 = (const float*)d_in[3];
    const float* b1 = (const float*)d_in[4];
    const float* W2 = (const float*)d_in[5];
    const float* b2 = (const float*)d_in[6];
    const float* W3 = (const float*)d_in[7];
    const float* b3 = (const float*)d_in[8];
    const float* Wl = (const float*)d_in[9];
    const float* bl = (const float*)d_in[10];
    float* out = (float*)d_out;

    char* ws     = (char*)d_ws;
    int*  cntblk = (int*)(ws + WS_CNT_OFF);
    int*  done   = (int*)(ws + WS_DONE_OFF);
    int*  lst    = (int*)(ws + WS_LST_OFF);
    int*  deg    = (int*)(ws + WS_DEG_OFF);

    collect<<<NB * WPG, 256, 0, stream>>>(ei, nidx, cntblk, lst, deg, done);

    count_tail<<<NB * WPG, 256, 0, stream>>>(x, ei, nidx, W1, b1, W2, b2,
                                             W3, b3, Wl, bl,
                                             cntblk, lst, deg, done, out);
}